// Round 21
// baseline (219.743 us; speedup 1.0000x reference)
//
#include <hip/hip_runtime.h>
#include <hip/hip_bf16.h>
#include <stdint.h>

#define NB 32
#define NR 2048
#define NC 64
#define NO 64
#define NK 16

using bf16x8 = __attribute__((ext_vector_type(8))) short;
using f32x4  = __attribute__((ext_vector_type(4))) float;

__device__ __forceinline__ uint32_t f2bf(float f) {
  uint32_t u = __builtin_bit_cast(uint32_t, f);
  return (u + 0x7fffu + ((u >> 16) & 1u)) >> 16;  // RNE (bit math)
}
__device__ __forceinline__ uint32_t packbf2(float lo, float hi) {
  return f2bf(lo) | (f2bf(hi) << 16);
}
// HW pair conversion (v_cvt_pk_bf16_f32); memcpy because __hip_bfloat162 is
// not trivially copyable.
__device__ __forceinline__ uint32_t cvtpk2(float lo, float hi) {
  float2 v; v.x = lo; v.y = hi;
  __hip_bfloat162 h = __float22bfloat162_rn(v);
  uint32_t r;
  __builtin_memcpy(&r, &h, 4);
  return r;
}

// x -> B-operand fragments with slot map c(kgrp,e) = ks*32 + e*4 + kgrp.
// xbf[r][(ks*2+bt)*512 + lane*8 + e] = bf16(x[bt*16+(lane&15)][c(lane>>4,e)]).
// The GEMM's W A-operand uses the SAME slot->c map, so the HW k-order cancels.
__global__ __launch_bounds__(256) void make_xbf(const float* __restrict__ x,
                                                ushort* __restrict__ xbf) {
  __shared__ float tile[32][72];
  const int r = blockIdx.x, t = threadIdx.x;
  {
    const int b = t >> 3, c0 = (t & 7) << 3;
    const float* xp = x + ((size_t)b * NR + r) * NC + c0;
    *(float4*)&tile[b][c0] = *(const float4*)xp;
    *(float4*)&tile[b][c0 + 4] = *(const float4*)(xp + 4);
  }
  __syncthreads();
  {
    const int ks = t >> 7, bt = (t >> 6) & 1, l = t & 63;
    const int kgrp = l >> 4;
    const int b = bt * 16 + (l & 15);
    const int cb = ks * 32 + kgrp;      // c = cb + e*4
    uint4 uv;
    uv.x = packbf2(tile[b][cb + 0], tile[b][cb + 4]);
    uv.y = packbf2(tile[b][cb + 8], tile[b][cb + 12]);
    uv.z = packbf2(tile[b][cb + 16], tile[b][cb + 20]);
    uv.w = packbf2(tile[b][cb + 24], tile[b][cb + 28]);
    *(uint4*)(xbf + (size_t)r * 2048 + t * 8) = uv;
  }
}

// 4-WAY o-SPLIT GEMM (extends R20's 2-way, which was +3.5us): one block =
// one (k,r) task; wave oh in 0..3 computes o-tile [oh*16, oh*16+16) with
// 4KB of W (acc[1][2], w32[8] per ks). VGPR ~65 -> more waves/CU and 4x
// independent per-task miss streams against the per-CU line-miss wall
// (R16-R20 evidence: ~12 GB/s/CU ingest regardless of staging mechanism).
// The 4 waves share one padded LDS epilogue tile; single barrier; stores
// stay full-o-row 1KB-contiguous.
__global__ __launch_bounds__(256) void priors_gemm(const ushort* __restrict__ xbf,
                                                   const float* __restrict__ W,
                                                   ushort* __restrict__ priors) {
  __shared__ ushort ldsE[32 * 72];  // [b][o] padded, 4.6KB per block
  const int oh = threadIdx.x >> 6, lane = threadIdx.x & 63;
  const int kgrp = lane >> 4, col = lane & 15;
  const int task = blockIdx.x;               // 16 consecutive tasks: same r, k=0..15
  const int k = task & 15, r = task >> 4;
  const float* wbase = W + ((size_t)(k * NR + r)) * 4096 + oh * 16;
  const ushort* xb = xbf + (size_t)r * 2048;

  // B-operand fragments (x), 8 x 16B loads, L3-resident (4x redundant/block)
  bf16x8 xfrag[2][2];  // [ks][bt]
#pragma unroll
  for (int ks = 0; ks < 2; ++ks)
#pragma unroll
    for (int bt = 0; bt < 2; ++bt)
      xfrag[ks][bt] = *(const bf16x8*)(xb + (ks * 2 + bt) * 512 + lane * 8);

  f32x4 acc[2];  // [bt] -- single o-tile per wave
#pragma unroll
  for (int bt = 0; bt < 2; ++bt) acc[bt] = f32x4{0.f, 0.f, 0.f, 0.f};

#pragma unroll
  for (int ks = 0; ks < 2; ++ks) {
    float w32[8];  // [e] -- 2KB distinct W per wave per ks
#pragma unroll
    for (int e = 0; e < 8; ++e)
      w32[e] = wbase[(ks * 32 + e * 4 + kgrp) * 64 + col];
    uint4 uv;
    uv.x = cvtpk2(w32[0], w32[1]);
    uv.y = cvtpk2(w32[2], w32[3]);
    uv.z = cvtpk2(w32[4], w32[5]);
    uv.w = cvtpk2(w32[6], w32[7]);
    bf16x8 af = __builtin_bit_cast(bf16x8, uv);
    acc[0] = __builtin_amdgcn_mfma_f32_16x16x32_bf16(af, xfrag[ks][0], acc[0], 0, 0, 0);
    acc[1] = __builtin_amdgcn_mfma_f32_16x16x32_bf16(af, xfrag[ks][1], acc[1], 0, 0, 0);
  }

  // epilogue: lane (kgrp,col) holds D rows o = oh*16 + kgrp*4 + reg,
  // col b = bt*16+col (m89-verified C/D layout). Block-shared buffer.
#pragma unroll
  for (int bt = 0; bt < 2; ++bt)
#pragma unroll
    for (int pr = 0; pr < 2; ++pr) {
      uint32_t u = cvtpk2(acc[bt][pr * 2], acc[bt][pr * 2 + 1]);
      const int b = bt * 16 + col, o = oh * 16 + kgrp * 4 + pr * 2;
      *(uint32_t*)(&ldsE[b * 72 + o]) = u;  // o even, 72 even -> dword aligned
    }
  __syncthreads();   // all four o-quarters of the tile in LDS

  // stores: wave oh writes rows [oh*8, oh*8+8); 1KB contiguous per instr
  ushort* pp = priors + ((size_t)(k * NR + r)) * 2048;
  {
    const int row = (lane >> 3) + oh * 8, cc = (lane & 7) * 8;
    uint4 v = *(const uint4*)(&ldsE[row * 72 + cc]);
    *(uint4*)(pp + row * 64 + cc) = v;
  }
}

// Routing passes (R17-exact separate kernels -- fusion measured +11.5us
// regression twice, R18/R19). Block per kb (k = kb>>5, b = kb&31).
// priors layout [k][r][b][o]. Lane: g = lane/8, sl = lane%8.
// PASS==1: phase A computes o0 = squash(mean_r p) in-block (priors read #1);
//          phase B: l = a_r = p.o0, stores a_r, writes o1 (priors read #2).
// PASS==2: l = a_r + p.o1; writes final output.
template <int PASS>
__global__ __launch_bounds__(256) void routing(const __hip_bfloat16* __restrict__ priors,
                                               float* __restrict__ Abuf,
                                               const float* __restrict__ o_prev,
                                               float* __restrict__ o_out) {
  __shared__ float o_lds[64];
  __shared__ float red_num[4][8][8];
  __shared__ float red_den[4];
  const int kb = blockIdx.x;
  const int k = kb >> 5, b = kb & 31;
  const int tid = threadIdx.x, w = tid >> 6, lane = tid & 63;
  const int g = lane >> 3, sl = lane & 7;
  const int rsub = w * 8 + g;
  const __hip_bfloat16* pbase = priors + (size_t)k * NR * NB * NO + (size_t)b * NO;
  float* ab = Abuf + (size_t)kb * NR;

  if (PASS == 1) {
    float sum[8];
#pragma unroll
    for (int j = 0; j < 8; ++j) sum[j] = 0.f;
    for (int it = 0; it < NR / 32; ++it) {
      const int r = it * 32 + rsub;
      uint4 pv = *(const uint4*)(pbase + (size_t)r * (NB * NO) + sl * 8);
      sum[0] += __builtin_bit_cast(float, pv.x << 16);
      sum[1] += __builtin_bit_cast(float, pv.x & 0xffff0000u);
      sum[2] += __builtin_bit_cast(float, pv.y << 16);
      sum[3] += __builtin_bit_cast(float, pv.y & 0xffff0000u);
      sum[4] += __builtin_bit_cast(float, pv.z << 16);
      sum[5] += __builtin_bit_cast(float, pv.z & 0xffff0000u);
      sum[6] += __builtin_bit_cast(float, pv.w << 16);
      sum[7] += __builtin_bit_cast(float, pv.w & 0xffff0000u);
    }
#pragma unroll
    for (int m = 8; m < 64; m <<= 1)
#pragma unroll
      for (int j = 0; j < 8; ++j) sum[j] += __shfl_xor(sum[j], m, 64);
    if (lane < 8) {
#pragma unroll
      for (int j = 0; j < 8; ++j) red_num[w][lane][j] = sum[j];
    }
    __syncthreads();
    if (tid < 64) {
      const int s_ = tid >> 3, j_ = tid & 7;
      float sv = (red_num[0][s_][j_] + red_num[1][s_][j_] +
                  red_num[2][s_][j_] + red_num[3][s_][j_]) * (1.f / (float)NR);
      float sq = sv * sv;
#pragma unroll
      for (int m = 1; m < 64; m <<= 1) sq += __shfl_xor(sq, m, 64);
      o_lds[tid] = (sq / (1.f + sq)) * rsqrtf(sq) * sv;  // squash
    }
    __syncthreads();
  } else {
    if (tid < 64) o_lds[tid] = o_prev[kb * 64 + tid];
    __syncthreads();
  }

  float os[8];
#pragma unroll
  for (int j = 0; j < 8; ++j) os[j] = o_lds[sl * 8 + j];

  float num[8];
#pragma unroll
  for (int j = 0; j < 8; ++j) num[j] = 0.f;
  float den = 0.f;

  for (int it = 0; it < NR / 32; ++it) {
    const int r = it * 32 + rsub;
    uint4 pv = *(const uint4*)(pbase + (size_t)r * (NB * NO) + sl * 8);
    float f[8];
    f[0] = __builtin_bit_cast(float, pv.x << 16);
    f[1] = __builtin_bit_cast(float, pv.x & 0xffff0000u);
    f[2] = __builtin_bit_cast(float, pv.y << 16);
    f[3] = __builtin_bit_cast(float, pv.y & 0xffff0000u);
    f[4] = __builtin_bit_cast(float, pv.z << 16);
    f[5] = __builtin_bit_cast(float, pv.z & 0xffff0000u);
    f[6] = __builtin_bit_cast(float, pv.w << 16);
    f[7] = __builtin_bit_cast(float, pv.w & 0xffff0000u);

    float d = 0.f;
#pragma unroll
    for (int j = 0; j < 8; ++j) d = fmaf(f[j], os[j], d);
#pragma unroll
    for (int m = 1; m < 8; m <<= 1) d += __shfl_xor(d, m, 64);

    float lg;
    if (PASS == 1) {
      lg = d;
      if (sl == 0) ab[r] = d;
    } else {
      lg = d + ab[r];
    }
    float e = __expf(lg);  // |lg| << 1, no max-subtraction needed
    den += e;
#pragma unroll
    for (int j = 0; j < 8; ++j) num[j] = fmaf(e, f[j], num[j]);
  }

#pragma unroll
  for (int m = 8; m < 64; m <<= 1) {
    den += __shfl_xor(den, m, 64);
#pragma unroll
    for (int j = 0; j < 8; ++j) num[j] += __shfl_xor(num[j], m, 64);
  }
  if (lane < 8) {
#pragma unroll
    for (int j = 0; j < 8; ++j) red_num[w][lane][j] = num[j];
    if (lane == 0) red_den[w] = den;
  }
  __syncthreads();

  if (tid < 64) {
    const int s_ = tid >> 3, j_ = tid & 7;
    float nm = red_num[0][s_][j_] + red_num[1][s_][j_] + red_num[2][s_][j_] + red_num[3][s_][j_];
    float dn = red_den[0] + red_den[1] + red_den[2] + red_den[3];
    float sv = nm / dn;
    float sq = sv * sv;
#pragma unroll
    for (int m = 1; m < 64; m <<= 1) sq += __shfl_xor(sq, m, 64);
    float ov = (sq / (1.f + sq)) * rsqrtf(sq) * sv;
    o_out[kb * 64 + tid] = ov;
  }
}

extern "C" void kernel_launch(void* const* d_in, const int* in_sizes, int n_in,
                              void* d_out, int out_size, void* d_ws, size_t ws_size,
                              hipStream_t stream) {
  const float* x = (const float*)d_in[0];          // [B][R][CIN]
  const float* W = (const float*)d_in[1];          // [K][R][CIN][COUT]
  float* out = (float*)d_out;                      // [K][B][COUT]
  char* ws = (char*)d_ws;

  size_t off = 0;
  ushort* xbf = (ushort*)(ws + off);               off += (size_t)NR * 2048 * 2;           // 8 MB
  ushort* priors = (ushort*)(ws + off);            off += (size_t)NK * NR * NB * NO * 2;   // 128 MB
  float* o1 = (float*)(ws + off);                  off += (size_t)NK * NB * NO * 4;        // 128 KB
  float* Abuf = (float*)(ws + off);                off += (size_t)NK * NB * NR * 4;        // 4 MB

  make_xbf<<<NR, 256, 0, stream>>>(x, xbf);
  priors_gemm<<<NR * NK, 256, 0, stream>>>(xbf, W, priors);
  routing<1><<<NK * NB, 256, 0, stream>>>((const __hip_bfloat16*)priors, Abuf, nullptr, o1);
  routing<2><<<NK * NB, 256, 0, stream>>>((const __hip_bfloat16*)priors, Abuf, o1, out);
}

// Round 22
// 216.000 us; speedup vs baseline: 1.0173x; 1.0173x over previous
//
#include <hip/hip_runtime.h>
#include <hip/hip_bf16.h>
#include <stdint.h>

#define NB 32
#define NR 2048
#define NC 64
#define NO 64
#define NK 16

using bf16x8 = __attribute__((ext_vector_type(8))) short;
using f32x4  = __attribute__((ext_vector_type(4))) float;

__device__ __forceinline__ uint32_t f2bf(float f) {
  uint32_t u = __builtin_bit_cast(uint32_t, f);
  return (u + 0x7fffu + ((u >> 16) & 1u)) >> 16;  // RNE (bit math)
}
__device__ __forceinline__ uint32_t packbf2(float lo, float hi) {
  return f2bf(lo) | (f2bf(hi) << 16);
}
// HW pair conversion (v_cvt_pk_bf16_f32); memcpy because __hip_bfloat162 is
// not trivially copyable.
__device__ __forceinline__ uint32_t cvtpk2(float lo, float hi) {
  float2 v; v.x = lo; v.y = hi;
  __hip_bfloat162 h = __float22bfloat162_rn(v);
  uint32_t r;
  __builtin_memcpy(&r, &h, 4);
  return r;
}

// x -> B-operand fragments with slot map c(kgrp,e) = ks*32 + e*4 + kgrp.
// xbf[r][(ks*2+bt)*512 + lane*8 + e] = bf16(x[bt*16+(lane&15)][c(lane>>4,e)]).
// The GEMM's W A-operand uses the SAME slot->c map, so the HW k-order cancels.
__global__ __launch_bounds__(256) void make_xbf(const float* __restrict__ x,
                                                ushort* __restrict__ xbf) {
  __shared__ float tile[32][72];
  const int r = blockIdx.x, t = threadIdx.x;
  {
    const int b = t >> 3, c0 = (t & 7) << 3;
    const float* xp = x + ((size_t)b * NR + r) * NC + c0;
    *(float4*)&tile[b][c0] = *(const float4*)xp;
    *(float4*)&tile[b][c0 + 4] = *(const float4*)(xp + 4);
  }
  __syncthreads();
  {
    const int ks = t >> 7, bt = (t >> 6) & 1, l = t & 63;
    const int kgrp = l >> 4;
    const int b = bt * 16 + (l & 15);
    const int cb = ks * 32 + kgrp;      // c = cb + e*4
    uint4 uv;
    uv.x = packbf2(tile[b][cb + 0], tile[b][cb + 4]);
    uv.y = packbf2(tile[b][cb + 8], tile[b][cb + 12]);
    uv.z = packbf2(tile[b][cb + 16], tile[b][cb + 20]);
    uv.w = packbf2(tile[b][cb + 24], tile[b][cb + 28]);
    *(uint4*)(xbf + (size_t)r * 2048 + t * 8) = uv;
  }
}

// R20-EXACT PAIRED-WAVE GEMM (best measured: 216.1us total; o-split sweep
// 1-way 219.6 / 2-way 216.1 / 4-way 219.7). Each (k,r) task split across an
// oh-pair of waves (8KB W each). W = A-operand direct global->VGPR dwords
// (the per-CU cold-miss service wall is invariant to staging mechanism,
// R4-R21); x = B-operand from xbf (L3-hot); pair-shared padded LDS epilogue;
// full-row 1KB-contiguous priors stores.
__global__ __launch_bounds__(256) void priors_gemm(const ushort* __restrict__ xbf,
                                                   const float* __restrict__ W,
                                                   ushort* __restrict__ priors) {
  __shared__ ushort ldsE[2][32 * 72];  // [pair][b][o] padded, 9KB
  const int w = threadIdx.x >> 6, lane = threadIdx.x & 63;
  const int p = w >> 1, oh = w & 1;          // pair id, o-half
  const int kgrp = lane >> 4, col = lane & 15;
  const int task = blockIdx.x * 2 + p;       // 16 consecutive tasks: same r, k=0..15
  const int k = task & 15, r = task >> 4;
  const float* wbase = W + ((size_t)(k * NR + r)) * 4096 + oh * 32;
  const ushort* xb = xbf + (size_t)r * 2048;

  // B-operand fragments (x), 8 x 16B loads, L3-resident
  bf16x8 xfrag[2][2];  // [ks][bt]
#pragma unroll
  for (int ks = 0; ks < 2; ++ks)
#pragma unroll
    for (int bt = 0; bt < 2; ++bt)
      xfrag[ks][bt] = *(const bf16x8*)(xb + (ks * 2 + bt) * 512 + lane * 8);

  f32x4 acc[2][2];  // [ot][bt], ot local (global o-tile = oh*2+ot)
#pragma unroll
  for (int ot = 0; ot < 2; ++ot)
#pragma unroll
    for (int bt = 0; bt < 2; ++bt) acc[ot][bt] = f32x4{0.f, 0.f, 0.f, 0.f};

#pragma unroll
  for (int ks = 0; ks < 2; ++ks) {
    float w32[2][8];  // [ot][e] -- 8KB distinct W per wave total
#pragma unroll
    for (int e = 0; e < 8; ++e) {
      const float* src = wbase + (ks * 32 + e * 4 + kgrp) * 64 + col;
#pragma unroll
      for (int ot = 0; ot < 2; ++ot) w32[ot][e] = src[ot * 16];
    }
#pragma unroll
    for (int ot = 0; ot < 2; ++ot) {
      uint4 uv;
      uv.x = cvtpk2(w32[ot][0], w32[ot][1]);
      uv.y = cvtpk2(w32[ot][2], w32[ot][3]);
      uv.z = cvtpk2(w32[ot][4], w32[ot][5]);
      uv.w = cvtpk2(w32[ot][6], w32[ot][7]);
      bf16x8 af = __builtin_bit_cast(bf16x8, uv);
      acc[ot][0] = __builtin_amdgcn_mfma_f32_16x16x32_bf16(af, xfrag[ks][0], acc[ot][0], 0, 0, 0);
      acc[ot][1] = __builtin_amdgcn_mfma_f32_16x16x32_bf16(af, xfrag[ks][1], acc[ot][1], 0, 0, 0);
    }
  }

  // epilogue: lane (kgrp,col) holds D rows o = (oh*2+ot)*16 + kgrp*4 + reg,
  // col b = bt*16+col (m89-verified C/D layout). Pair-shared buffer.
  ushort* ep = &ldsE[p][0];
#pragma unroll
  for (int ot = 0; ot < 2; ++ot)
#pragma unroll
    for (int bt = 0; bt < 2; ++bt)
#pragma unroll
      for (int pr = 0; pr < 2; ++pr) {
        uint32_t u = cvtpk2(acc[ot][bt][pr * 2], acc[ot][bt][pr * 2 + 1]);
        const int b = bt * 16 + col, o = (oh * 2 + ot) * 16 + kgrp * 4 + pr * 2;
        *(uint32_t*)(&ep[b * 72 + o]) = u;  // o even, 72 even -> dword aligned
      }
  __syncthreads();   // both halves of each pair's tile in LDS

  // stores: pair splits rows by oh; 1KB contiguous per instr (full o rows)
  ushort* pp = priors + ((size_t)(k * NR + r)) * 2048;
#pragma unroll
  for (int i = 0; i < 2; ++i) {
    const int row = (lane >> 3) + (i + oh * 2) * 8, cc = (lane & 7) * 8;
    uint4 v = *(const uint4*)(&ep[row * 72 + cc]);
    *(uint4*)(pp + row * 64 + cc) = v;
  }
}

// Routing passes (R17-exact separate kernels -- fusion measured +11.5us
// regression twice, R18/R19). Block per kb (k = kb>>5, b = kb&31).
// priors layout [k][r][b][o]. Lane: g = lane/8, sl = lane%8.
// PASS==1: phase A computes o0 = squash(mean_r p) in-block (priors read #1);
//          phase B: l = a_r = p.o0, stores a_r, writes o1 (priors read #2).
// PASS==2: l = a_r + p.o1; writes final output.
template <int PASS>
__global__ __launch_bounds__(256) void routing(const __hip_bfloat16* __restrict__ priors,
                                               float* __restrict__ Abuf,
                                               const float* __restrict__ o_prev,
                                               float* __restrict__ o_out) {
  __shared__ float o_lds[64];
  __shared__ float red_num[4][8][8];
  __shared__ float red_den[4];
  const int kb = blockIdx.x;
  const int k = kb >> 5, b = kb & 31;
  const int tid = threadIdx.x, w = tid >> 6, lane = tid & 63;
  const int g = lane >> 3, sl = lane & 7;
  const int rsub = w * 8 + g;
  const __hip_bfloat16* pbase = priors + (size_t)k * NR * NB * NO + (size_t)b * NO;
  float* ab = Abuf + (size_t)kb * NR;

  if (PASS == 1) {
    float sum[8];
#pragma unroll
    for (int j = 0; j < 8; ++j) sum[j] = 0.f;
    for (int it = 0; it < NR / 32; ++it) {
      const int r = it * 32 + rsub;
      uint4 pv = *(const uint4*)(pbase + (size_t)r * (NB * NO) + sl * 8);
      sum[0] += __builtin_bit_cast(float, pv.x << 16);
      sum[1] += __builtin_bit_cast(float, pv.x & 0xffff0000u);
      sum[2] += __builtin_bit_cast(float, pv.y << 16);
      sum[3] += __builtin_bit_cast(float, pv.y & 0xffff0000u);
      sum[4] += __builtin_bit_cast(float, pv.z << 16);
      sum[5] += __builtin_bit_cast(float, pv.z & 0xffff0000u);
      sum[6] += __builtin_bit_cast(float, pv.w << 16);
      sum[7] += __builtin_bit_cast(float, pv.w & 0xffff0000u);
    }
#pragma unroll
    for (int m = 8; m < 64; m <<= 1)
#pragma unroll
      for (int j = 0; j < 8; ++j) sum[j] += __shfl_xor(sum[j], m, 64);
    if (lane < 8) {
#pragma unroll
      for (int j = 0; j < 8; ++j) red_num[w][lane][j] = sum[j];
    }
    __syncthreads();
    if (tid < 64) {
      const int s_ = tid >> 3, j_ = tid & 7;
      float sv = (red_num[0][s_][j_] + red_num[1][s_][j_] +
                  red_num[2][s_][j_] + red_num[3][s_][j_]) * (1.f / (float)NR);
      float sq = sv * sv;
#pragma unroll
      for (int m = 1; m < 64; m <<= 1) sq += __shfl_xor(sq, m, 64);
      o_lds[tid] = (sq / (1.f + sq)) * rsqrtf(sq) * sv;  // squash
    }
    __syncthreads();
  } else {
    if (tid < 64) o_lds[tid] = o_prev[kb * 64 + tid];
    __syncthreads();
  }

  float os[8];
#pragma unroll
  for (int j = 0; j < 8; ++j) os[j] = o_lds[sl * 8 + j];

  float num[8];
#pragma unroll
  for (int j = 0; j < 8; ++j) num[j] = 0.f;
  float den = 0.f;

  for (int it = 0; it < NR / 32; ++it) {
    const int r = it * 32 + rsub;
    uint4 pv = *(const uint4*)(pbase + (size_t)r * (NB * NO) + sl * 8);
    float f[8];
    f[0] = __builtin_bit_cast(float, pv.x << 16);
    f[1] = __builtin_bit_cast(float, pv.x & 0xffff0000u);
    f[2] = __builtin_bit_cast(float, pv.y << 16);
    f[3] = __builtin_bit_cast(float, pv.y & 0xffff0000u);
    f[4] = __builtin_bit_cast(float, pv.z << 16);
    f[5] = __builtin_bit_cast(float, pv.z & 0xffff0000u);
    f[6] = __builtin_bit_cast(float, pv.w << 16);
    f[7] = __builtin_bit_cast(float, pv.w & 0xffff0000u);

    float d = 0.f;
#pragma unroll
    for (int j = 0; j < 8; ++j) d = fmaf(f[j], os[j], d);
#pragma unroll
    for (int m = 1; m < 8; m <<= 1) d += __shfl_xor(d, m, 64);

    float lg;
    if (PASS == 1) {
      lg = d;
      if (sl == 0) ab[r] = d;
    } else {
      lg = d + ab[r];
    }
    float e = __expf(lg);  // |lg| << 1, no max-subtraction needed
    den += e;
#pragma unroll
    for (int j = 0; j < 8; ++j) num[j] = fmaf(e, f[j], num[j]);
  }

#pragma unroll
  for (int m = 8; m < 64; m <<= 1) {
    den += __shfl_xor(den, m, 64);
#pragma unroll
    for (int j = 0; j < 8; ++j) num[j] += __shfl_xor(num[j], m, 64);
  }
  if (lane < 8) {
#pragma unroll
    for (int j = 0; j < 8; ++j) red_num[w][lane][j] = num[j];
    if (lane == 0) red_den[w] = den;
  }
  __syncthreads();

  if (tid < 64) {
    const int s_ = tid >> 3, j_ = tid & 7;
    float nm = red_num[0][s_][j_] + red_num[1][s_][j_] + red_num[2][s_][j_] + red_num[3][s_][j_];
    float dn = red_den[0] + red_den[1] + red_den[2] + red_den[3];
    float sv = nm / dn;
    float sq = sv * sv;
#pragma unroll
    for (int m = 1; m < 64; m <<= 1) sq += __shfl_xor(sq, m, 64);
    float ov = (sq / (1.f + sq)) * rsqrtf(sq) * sv;
    o_out[kb * 64 + tid] = ov;
  }
}

extern "C" void kernel_launch(void* const* d_in, const int* in_sizes, int n_in,
                              void* d_out, int out_size, void* d_ws, size_t ws_size,
                              hipStream_t stream) {
  const float* x = (const float*)d_in[0];          // [B][R][CIN]
  const float* W = (const float*)d_in[1];          // [K][R][CIN][COUT]
  float* out = (float*)d_out;                      // [K][B][COUT]
  char* ws = (char*)d_ws;

  size_t off = 0;
  ushort* xbf = (ushort*)(ws + off);               off += (size_t)NR * 2048 * 2;           // 8 MB
  ushort* priors = (ushort*)(ws + off);            off += (size_t)NK * NR * NB * NO * 2;   // 128 MB
  float* o1 = (float*)(ws + off);                  off += (size_t)NK * NB * NO * 4;        // 128 KB
  float* Abuf = (float*)(ws + off);                off += (size_t)NK * NB * NR * 4;        // 4 MB

  make_xbf<<<NR, 256, 0, stream>>>(x, xbf);
  priors_gemm<<<(NR * NK) / 2, 256, 0, stream>>>(xbf, W, priors);
  routing<1><<<NK * NB, 256, 0, stream>>>((const __hip_bfloat16*)priors, Abuf, nullptr, o1);
  routing<2><<<NK * NB, 256, 0, stream>>>((const __hip_bfloat16*)priors, Abuf, o1, out);
}